// Round 1
// baseline (929.066 us; speedup 1.0000x reference)
//
#include <hip/hip_runtime.h>
#include <hip/hip_bf16.h>
#include <math.h>

#define NTOK 2048
#define HID 2048
#define NEXP 8
#define FINT 768
#define TOPK 2

#define MT 128
#define NT 64
#define KT 16

// ---------------- workspace layout (bytes) ----------------
// 0       : topk_idx  int[NTOK*2]          16384
// 16384   : topk_w    f32[NTOK*2]          16384
// 32768   : counts    int[8]
// 32800   : offsets   int[8]
// 65536   : elist_t   int[8*2048]          65536
// 131072  : elist_w   f32[8*2048]          65536
// 196608  : row_token int[4096]            16384
// 212992  : row_w     f32[4096]            16384
// 262144  : h_buf     f32[4096*768]        12582912
// total ~12.85 MB

__global__ void moe_router_kernel(const float* __restrict__ x,
                                  const float* __restrict__ gw,
                                  float* __restrict__ logits_out,
                                  int* __restrict__ topk_idx,
                                  float* __restrict__ topk_w) {
    int t = blockIdx.x;
    int tid = threadIdx.x;          // 256
    int e = tid >> 5;               // 0..7
    int lane32 = tid & 31;
    const float* xr = x + (size_t)t * HID;
    const float* gr = gw + (size_t)e * HID;
    float acc = 0.f;
    for (int h = lane32; h < HID; h += 32) acc += xr[h] * gr[h];
    #pragma unroll
    for (int off = 16; off > 0; off >>= 1) acc += __shfl_xor(acc, off);
    __shared__ float slog[NEXP];
    if (lane32 == 0) slog[e] = acc;
    __syncthreads();
    if (tid == 0) {
        float l[NEXP], m = -1e30f;
        #pragma unroll
        for (int i = 0; i < NEXP; ++i) { l[i] = slog[i]; m = fmaxf(m, l[i]); }
        float p[NEXP];
        #pragma unroll
        for (int i = 0; i < NEXP; ++i) p[i] = expf(l[i] - m);
        int i0 = 0;
        #pragma unroll
        for (int i = 1; i < NEXP; ++i) if (p[i] > p[i0]) i0 = i;
        int i1 = (i0 == 0) ? 1 : 0;
        #pragma unroll
        for (int i = 0; i < NEXP; ++i) if (i != i0 && p[i] > p[i1]) i1 = i;
        float w0 = p[i0], w1 = p[i1], sw = w0 + w1;
        topk_idx[t * 2 + 0] = i0;
        topk_idx[t * 2 + 1] = i1;
        topk_w[t * 2 + 0] = w0 / sw;
        topk_w[t * 2 + 1] = w1 / sw;
        #pragma unroll
        for (int i = 0; i < NEXP; ++i) logits_out[(size_t)t * NEXP + i] = l[i];
    }
}

__global__ void moe_build_kernel(const int* __restrict__ topk_idx,
                                 const float* __restrict__ topk_w,
                                 int* __restrict__ counts,
                                 int* __restrict__ offsets,
                                 int* __restrict__ elist_t,
                                 float* __restrict__ elist_w,
                                 int* __restrict__ row_token,
                                 float* __restrict__ row_w) {
    __shared__ int scnt[NEXP];
    __shared__ int soff[NEXP];
    int tid = threadIdx.x; // 1024
    if (tid < NEXP) scnt[tid] = 0;
    __syncthreads();
    for (int t = tid; t < NTOK; t += 1024) {
        #pragma unroll
        for (int k = 0; k < TOPK; ++k) {
            int e = topk_idx[t * 2 + k];
            float w = topk_w[t * 2 + k];
            int slot = atomicAdd(&scnt[e], 1);
            elist_t[e * NTOK + slot] = t;
            elist_w[e * NTOK + slot] = w;
        }
    }
    __syncthreads();
    if (tid == 0) {
        int o = 0;
        for (int e = 0; e < NEXP; ++e) {
            soff[e] = o; offsets[e] = o; counts[e] = scnt[e]; o += scnt[e];
        }
    }
    __syncthreads();
    for (int e = 0; e < NEXP; ++e) {
        int c = scnt[e], o = soff[e];
        for (int s = tid; s < c; s += 1024) {
            row_token[o + s] = elist_t[e * NTOK + s];
            row_w[o + s]     = elist_w[e * NTOK + s];
        }
    }
}

// h = silu(x @ Wg) * (x @ Wu)   per expert, gathered token rows
__global__ __launch_bounds__(256) void moe_stage_a(
        const float* __restrict__ x,
        const float* __restrict__ w_gate,
        const float* __restrict__ w_up,
        const int* __restrict__ counts,
        const int* __restrict__ offsets,
        const int* __restrict__ row_token,
        float* __restrict__ h_buf) {
    int e = blockIdx.x, mt = blockIdx.y, nt = blockIdx.z;
    int count = counts[e];
    int m0 = mt * MT;
    if (m0 >= count) return;
    int off = offsets[e];
    int n0 = nt * NT;
    int mcnt = min(MT, count - m0);
    int tid = threadIdx.x;

    __shared__ float As[KT][MT];
    __shared__ float Bg[KT][NT];
    __shared__ float Bu[KT][NT];
    __shared__ int toks[MT];

    if (tid < MT) toks[tid] = row_token[off + m0 + (tid < mcnt ? tid : 0)];
    __syncthreads();

    int tm = tid >> 4;   // 0..15 -> m block of 8
    int tn = tid & 15;   // 0..15 -> n block of 4
    float accg[8][4] = {{0}};
    float accu[8][4] = {{0}};

    const float* wg = w_gate + (size_t)e * HID * FINT + n0;
    const float* wu = w_up   + (size_t)e * HID * FINT + n0;

    for (int k0 = 0; k0 < HID; k0 += KT) {
        #pragma unroll
        for (int i = 0; i < 2; ++i) {
            int s = tid * 2 + i;          // 0..511
            int m = s >> 2;               // 0..127
            int kq = (s & 3) * 4;         // 0,4,8,12
            float4 v = *reinterpret_cast<const float4*>(&x[(size_t)toks[m] * HID + k0 + kq]);
            As[kq + 0][m] = v.x; As[kq + 1][m] = v.y;
            As[kq + 2][m] = v.z; As[kq + 3][m] = v.w;
        }
        {
            int k = tid >> 4;             // 0..15
            int nn = (tid & 15) * 4;      // 0..60
            *reinterpret_cast<float4*>(&Bg[k][nn]) =
                *reinterpret_cast<const float4*>(&wg[(size_t)(k0 + k) * FINT + nn]);
            *reinterpret_cast<float4*>(&Bu[k][nn]) =
                *reinterpret_cast<const float4*>(&wu[(size_t)(k0 + k) * FINT + nn]);
        }
        __syncthreads();
        #pragma unroll
        for (int k = 0; k < KT; ++k) {
            float a[8], bg[4], bu[4];
            *reinterpret_cast<float4*>(&a[0]) = *reinterpret_cast<const float4*>(&As[k][tm * 8 + 0]);
            *reinterpret_cast<float4*>(&a[4]) = *reinterpret_cast<const float4*>(&As[k][tm * 8 + 4]);
            *reinterpret_cast<float4*>(&bg[0]) = *reinterpret_cast<const float4*>(&Bg[k][tn * 4]);
            *reinterpret_cast<float4*>(&bu[0]) = *reinterpret_cast<const float4*>(&Bu[k][tn * 4]);
            #pragma unroll
            for (int i = 0; i < 8; ++i)
                #pragma unroll
                for (int j = 0; j < 4; ++j) {
                    accg[i][j] += a[i] * bg[j];
                    accu[i][j] += a[i] * bu[j];
                }
        }
        __syncthreads();
    }

    #pragma unroll
    for (int i = 0; i < 8; ++i) {
        int m = tm * 8 + i;
        if (m < mcnt) {
            float4 hv;
            float g, s;
            g = accg[i][0]; s = g / (1.f + expf(-g)); hv.x = s * accu[i][0];
            g = accg[i][1]; s = g / (1.f + expf(-g)); hv.y = s * accu[i][1];
            g = accg[i][2]; s = g / (1.f + expf(-g)); hv.z = s * accu[i][2];
            g = accg[i][3]; s = g / (1.f + expf(-g)); hv.w = s * accu[i][3];
            *reinterpret_cast<float4*>(&h_buf[(size_t)(off + m0 + m) * FINT + n0 + tn * 4]) = hv;
        }
    }
}

// out[tok] += w * (h @ Wd)
__global__ __launch_bounds__(256) void moe_stage_b(
        const float* __restrict__ h_buf,
        const float* __restrict__ w_down,
        const int* __restrict__ counts,
        const int* __restrict__ offsets,
        const int* __restrict__ row_token,
        const float* __restrict__ row_w,
        float* __restrict__ out) {
    int e = blockIdx.x, mt = blockIdx.y, nt = blockIdx.z;
    int count = counts[e];
    int m0 = mt * MT;
    if (m0 >= count) return;
    int off = offsets[e];
    int n0 = nt * NT;
    int mcnt = min(MT, count - m0);
    int tid = threadIdx.x;

    __shared__ float As[KT][MT];
    __shared__ float Bs[KT][NT];
    __shared__ int toks[MT];
    __shared__ float rws[MT];

    if (tid < MT) {
        int m = tid < mcnt ? tid : 0;
        toks[tid] = row_token[off + m0 + m];
        rws[tid]  = row_w[off + m0 + m];
    }
    __syncthreads();

    int tm = tid >> 4, tn = tid & 15;
    float acc[8][4] = {{0}};

    const float* wd = w_down + (size_t)e * FINT * HID + n0;
    const float* ab = h_buf + (size_t)(off + m0) * FINT;

    for (int k0 = 0; k0 < FINT; k0 += KT) {
        #pragma unroll
        for (int i = 0; i < 2; ++i) {
            int s = tid * 2 + i;
            int m = s >> 2;
            int kq = (s & 3) * 4;
            int mm = m < mcnt ? m : 0;   // avoid OOB past last expert rows
            float4 v = *reinterpret_cast<const float4*>(&ab[(size_t)mm * FINT + k0 + kq]);
            As[kq + 0][m] = v.x; As[kq + 1][m] = v.y;
            As[kq + 2][m] = v.z; As[kq + 3][m] = v.w;
        }
        {
            int k = tid >> 4;
            int nn = (tid & 15) * 4;
            *reinterpret_cast<float4*>(&Bs[k][nn]) =
                *reinterpret_cast<const float4*>(&wd[(size_t)(k0 + k) * HID + nn]);
        }
        __syncthreads();
        #pragma unroll
        for (int k = 0; k < KT; ++k) {
            float a[8], b[4];
            *reinterpret_cast<float4*>(&a[0]) = *reinterpret_cast<const float4*>(&As[k][tm * 8 + 0]);
            *reinterpret_cast<float4*>(&a[4]) = *reinterpret_cast<const float4*>(&As[k][tm * 8 + 4]);
            *reinterpret_cast<float4*>(&b[0]) = *reinterpret_cast<const float4*>(&Bs[k][tn * 4]);
            #pragma unroll
            for (int i = 0; i < 8; ++i)
                #pragma unroll
                for (int j = 0; j < 4; ++j) acc[i][j] += a[i] * b[j];
        }
        __syncthreads();
    }

    #pragma unroll
    for (int i = 0; i < 8; ++i) {
        int m = tm * 8 + i;
        if (m < mcnt) {
            float w = rws[m];
            float* op = &out[(size_t)toks[m] * HID + n0 + tn * 4];
            #pragma unroll
            for (int j = 0; j < 4; ++j) atomicAdd(&op[j], w * acc[i][j]);
        }
    }
}

extern "C" void kernel_launch(void* const* d_in, const int* in_sizes, int n_in,
                              void* d_out, int out_size, void* d_ws, size_t ws_size,
                              hipStream_t stream) {
    const float* x       = (const float*)d_in[0];  // [2,1024,2048]
    const float* gate_w  = (const float*)d_in[1];  // [8,2048]
    const float* w_gate  = (const float*)d_in[2];  // [8,2048,768]
    const float* w_up    = (const float*)d_in[3];  // [8,2048,768]
    const float* w_down  = (const float*)d_in[4];  // [8,768,2048]
    float* out = (float*)d_out;                    // 4194304 out + 16384 logits

    char* ws = (char*)d_ws;
    int*   topk_idx  = (int*)  (ws + 0);
    float* topk_w    = (float*)(ws + 16384);
    int*   counts    = (int*)  (ws + 32768);
    int*   offsets   = (int*)  (ws + 32800);
    int*   elist_t   = (int*)  (ws + 65536);
    float* elist_w   = (float*)(ws + 131072);
    int*   row_token = (int*)  (ws + 196608);
    float* row_w     = (float*)(ws + 212992);
    float* h_buf     = (float*)(ws + 262144);

    float* logits_out = out + (size_t)NTOK * HID;

    // zero the accumulated output region (logits are fully overwritten)
    hipMemsetAsync(out, 0, (size_t)NTOK * HID * sizeof(float), stream);

    moe_router_kernel<<<NTOK, 256, 0, stream>>>(x, gate_w, logits_out, topk_idx, topk_w);
    moe_build_kernel<<<1, 1024, 0, stream>>>(topk_idx, topk_w, counts, offsets,
                                             elist_t, elist_w, row_token, row_w);
    dim3 gridA(NEXP, (NTOK + MT - 1) / MT, FINT / NT);
    moe_stage_a<<<gridA, 256, 0, stream>>>(x, w_gate, w_up, counts, offsets, row_token, h_buf);
    dim3 gridB(NEXP, (NTOK + MT - 1) / MT, HID / NT);
    moe_stage_b<<<gridB, 256, 0, stream>>>(h_buf, w_down, counts, offsets, row_token, row_w, out);
}

// Round 2
// 196.026 us; speedup vs baseline: 4.7395x; 4.7395x over previous
//
#include <hip/hip_runtime.h>
#include <hip/hip_bf16.h>
#include <math.h>

#define NTOK 2048
#define HID 2048
#define NEXP 8
#define FINT 768
#define TOPK 2

typedef __attribute__((ext_vector_type(8))) short bf16x8;
typedef __attribute__((ext_vector_type(4))) float f32x4;

static __device__ __forceinline__ unsigned short f2bf(float f) {
    union { float f; unsigned u; } v; v.f = f;
    unsigned r = v.u + 0x7fffu + ((v.u >> 16) & 1u);
    return (unsigned short)(r >> 16);
}

static __device__ __forceinline__ void gl16(const void* g, void* l) {
    __builtin_amdgcn_global_load_lds(
        (const __attribute__((address_space(1))) unsigned int*)g,
        (__attribute__((address_space(3))) unsigned int*)(uintptr_t)l,
        16, 0, 0);
}

// ---------------- workspace layout (bytes) ----------------
// shared header (both paths):
// 0       : topk_idx  int[4096]
// 16384   : topk_w    f32[4096]
// 32768   : counts    int[8]
// 32800   : offsets   int[8]
// 33024   : row_token int[4096]
// 49408   : row_w     f32[4096]
// 65792   : elist_t   int[8*2048]
// 131328  : elist_w   f32[8*2048]
// bf16 path:
// 196864  : x_bf16    [2048][2048]        8388608
// 8585472 : wg_t      [8][768][2048] bf16 25165824
// 33751296: wu_t      [8][768][2048] bf16 25165824
// 58917120: wd_t      [8][2048][768] bf16 25165824
// 84082944: h_buf     [4096+64][768] bf16 6389760  -> end 90472704
// f32 fallback path reuses 196864.. for f32 h_buf (12.58MB)

__global__ void moe_router_kernel(const float* __restrict__ x,
                                  const float* __restrict__ gw,
                                  float* __restrict__ logits_out,
                                  int* __restrict__ topk_idx,
                                  float* __restrict__ topk_w) {
    int t = blockIdx.x;
    int tid = threadIdx.x;          // 256
    int e = tid >> 5;               // 0..7
    int lane32 = tid & 31;
    const float* xr = x + (size_t)t * HID;
    const float* gr = gw + (size_t)e * HID;
    float acc = 0.f;
    for (int h = lane32; h < HID; h += 32) acc += xr[h] * gr[h];
    #pragma unroll
    for (int off = 16; off > 0; off >>= 1) acc += __shfl_xor(acc, off);
    __shared__ float slog[NEXP];
    if (lane32 == 0) slog[e] = acc;
    __syncthreads();
    if (tid == 0) {
        float l[NEXP], m = -1e30f;
        #pragma unroll
        for (int i = 0; i < NEXP; ++i) { l[i] = slog[i]; m = fmaxf(m, l[i]); }
        float p[NEXP];
        #pragma unroll
        for (int i = 0; i < NEXP; ++i) p[i] = expf(l[i] - m);
        int i0 = 0;
        #pragma unroll
        for (int i = 1; i < NEXP; ++i) if (p[i] > p[i0]) i0 = i;
        int i1 = (i0 == 0) ? 1 : 0;
        #pragma unroll
        for (int i = 0; i < NEXP; ++i) if (i != i0 && p[i] > p[i1]) i1 = i;
        float w0 = p[i0], w1 = p[i1], sw = w0 + w1;
        topk_idx[t * 2 + 0] = i0;
        topk_idx[t * 2 + 1] = i1;
        topk_w[t * 2 + 0] = w0 / sw;
        topk_w[t * 2 + 1] = w1 / sw;
        #pragma unroll
        for (int i = 0; i < NEXP; ++i) logits_out[(size_t)t * NEXP + i] = l[i];
    }
}

__global__ void moe_build_kernel(const int* __restrict__ topk_idx,
                                 const float* __restrict__ topk_w,
                                 int* __restrict__ counts,
                                 int* __restrict__ offsets,
                                 int* __restrict__ elist_t,
                                 float* __restrict__ elist_w,
                                 int* __restrict__ row_token,
                                 float* __restrict__ row_w) {
    __shared__ int scnt[NEXP];
    __shared__ int soff[NEXP];
    int tid = threadIdx.x; // 1024
    if (tid < NEXP) scnt[tid] = 0;
    __syncthreads();
    for (int t = tid; t < NTOK; t += 1024) {
        #pragma unroll
        for (int k = 0; k < TOPK; ++k) {
            int e = topk_idx[t * 2 + k];
            float w = topk_w[t * 2 + k];
            int slot = atomicAdd(&scnt[e], 1);
            elist_t[e * NTOK + slot] = t;
            elist_w[e * NTOK + slot] = w;
        }
    }
    __syncthreads();
    if (tid == 0) {
        int o = 0;
        for (int e = 0; e < NEXP; ++e) {
            soff[e] = o; offsets[e] = o; counts[e] = scnt[e]; o += scnt[e];
        }
    }
    __syncthreads();
    for (int e = 0; e < NEXP; ++e) {
        int c = scnt[e], o = soff[e];
        for (int s = tid; s < c; s += 1024) {
            row_token[o + s] = elist_t[e * NTOK + s];
            row_w[o + s]     = elist_w[e * NTOK + s];
        }
    }
}

// ---------------- bf16 pre-passes ----------------

__global__ __launch_bounds__(256) void cvt_x_kernel(const float* __restrict__ src,
                                                    unsigned short* __restrict__ dst) {
    size_t i = ((size_t)blockIdx.x * 256 + threadIdx.x) * 8;
    float4 a = *(const float4*)&src[i];
    float4 b = *(const float4*)&src[i + 4];
    ushort4 o1 = make_ushort4(f2bf(a.x), f2bf(a.y), f2bf(a.z), f2bf(a.w));
    ushort4 o2 = make_ushort4(f2bf(b.x), f2bf(b.y), f2bf(b.z), f2bf(b.w));
    *(ushort4*)&dst[i] = o1;
    *(ushort4*)&dst[i + 4] = o2;
}

// src [z][R][C] f32 -> dst [z][C][R] bf16   (R,C multiples of 64)
__global__ __launch_bounds__(256) void transpose_cvt_kernel(const float* __restrict__ src,
                                                            unsigned short* __restrict__ dst,
                                                            int R, int C) {
    int e = blockIdx.z;
    int r0 = blockIdx.x * 64, c0 = blockIdx.y * 64;
    src += (size_t)e * R * C;
    dst += (size_t)e * R * C;
    __shared__ unsigned short tile[64][68];   // 136B rows: 8B-aligned, low conflict
    int tid = threadIdx.x;
    {
        int row = tid >> 2, cq = (tid & 3) * 16;
        #pragma unroll
        for (int i = 0; i < 4; ++i) {
            float4 v = *(const float4*)&src[(size_t)(r0 + row) * C + c0 + cq + i * 4];
            *(ushort4*)&tile[row][cq + i * 4] =
                make_ushort4(f2bf(v.x), f2bf(v.y), f2bf(v.z), f2bf(v.w));
        }
    }
    __syncthreads();
    {
        int c = tid >> 2, rq = (tid & 3) * 16;
        #pragma unroll
        for (int i = 0; i < 4; ++i) {
            ushort4 o = make_ushort4(tile[rq + i * 4 + 0][c], tile[rq + i * 4 + 1][c],
                                     tile[rq + i * 4 + 2][c], tile[rq + i * 4 + 3][c]);
            *(ushort4*)&dst[(size_t)(c0 + c) * R + r0 + rq + i * 4] = o;
        }
    }
}

// ---------------- MFMA stage A: h = silu(x*Wg) * (x*Wu) ----------------
// tiles: M=64 (gathered tokens), N=64 (inter cols), BK=64; 4 waves 2x2
__global__ __launch_bounds__(256) void moe_stage_a_mfma(
        const unsigned short* __restrict__ xb,    // [2048][2048]
        const unsigned short* __restrict__ wgt,   // [8][768][2048]
        const unsigned short* __restrict__ wut,   // [8][768][2048]
        const int* __restrict__ counts,
        const int* __restrict__ offsets,
        const int* __restrict__ row_token,
        unsigned short* __restrict__ h_buf) {     // [4160][768]
    int e = blockIdx.x, mt = blockIdx.y, nt = blockIdx.z;
    int count = counts[e];
    int m0 = mt * 64;
    if (m0 >= count) return;
    int off = offsets[e];
    int n0 = nt * 64;
    int mcnt = min(64, count - m0);
    int tid = threadIdx.x;

    __shared__ __align__(16) unsigned short As[64 * 64];
    __shared__ __align__(16) unsigned short Bg[64 * 64];
    __shared__ __align__(16) unsigned short Bu[64 * 64];
    __shared__ int toks[64];
    if (tid < 64) toks[tid] = row_token[off + m0 + min(tid, mcnt - 1)];
    __syncthreads();

    int w = tid >> 6, l = tid & 63;
    int wr = w >> 1, wc = w & 1;
    int lr = l & 15, lh = l >> 4;
    int rA = w * 8 + (l >> 3);    // staging row (0..31), +32 per issue
    int cA = l & 7;               // physical 16B chunk within 128B row

    const unsigned short* wgE = wgt + (size_t)e * FINT * HID + (size_t)n0 * HID;
    const unsigned short* wuE = wut + (size_t)e * FINT * HID + (size_t)n0 * HID;

    f32x4 gacc[2][2] = {};
    f32x4 uacc[2][2] = {};

    for (int k0 = 0; k0 < HID; k0 += 64) {
        #pragma unroll
        for (int i = 0; i < 2; ++i) {
            int row = 32 * i + rA;
            int sc = (cA ^ (row & 7)) << 3;      // source chunk -> elem offset
            char* dA = (char*)As + (size_t)(32 * i + w * 8) * 128;
            gl16(xb + (size_t)toks[row] * HID + k0 + sc, dA);
            char* dG = (char*)Bg + (size_t)(32 * i + w * 8) * 128;
            gl16(wgE + (size_t)row * HID + k0 + sc, dG);
            char* dU = (char*)Bu + (size_t)(32 * i + w * 8) * 128;
            gl16(wuE + (size_t)row * HID + k0 + sc, dU);
        }
        __syncthreads();
        #pragma unroll
        for (int ks = 0; ks < 2; ++ks) {
            bf16x8 af[2], bg[2], bu[2];
            #pragma unroll
            for (int mi = 0; mi < 2; ++mi) {
                int row = wr * 32 + mi * 16 + lr;
                int byte = row * 128 + ((ks * 64 + lh * 16) ^ ((row & 7) << 4));
                af[mi] = *(const bf16x8*)((const char*)As + byte);
            }
            #pragma unroll
            for (int ni = 0; ni < 2; ++ni) {
                int row = wc * 32 + ni * 16 + lr;
                int byte = row * 128 + ((ks * 64 + lh * 16) ^ ((row & 7) << 4));
                bg[ni] = *(const bf16x8*)((const char*)Bg + byte);
                bu[ni] = *(const bf16x8*)((const char*)Bu + byte);
            }
            #pragma unroll
            for (int mi = 0; mi < 2; ++mi)
                #pragma unroll
                for (int ni = 0; ni < 2; ++ni) {
                    gacc[mi][ni] = __builtin_amdgcn_mfma_f32_16x16x32_bf16(af[mi], bg[ni], gacc[mi][ni], 0, 0, 0);
                    uacc[mi][ni] = __builtin_amdgcn_mfma_f32_16x16x32_bf16(af[mi], bu[ni], uacc[mi][ni], 0, 0, 0);
                }
        }
        __syncthreads();
    }

    #pragma unroll
    for (int mi = 0; mi < 2; ++mi)
        #pragma unroll
        for (int ni = 0; ni < 2; ++ni)
            #pragma unroll
            for (int j = 0; j < 4; ++j) {
                int row = wr * 32 + mi * 16 + lh * 4 + j;
                if (row < mcnt) {
                    int col = wc * 32 + ni * 16 + lr;
                    float g = gacc[mi][ni][j], u = uacc[mi][ni][j];
                    float hv = g / (1.f + expf(-g)) * u;
                    h_buf[(size_t)(off + m0 + row) * FINT + n0 + col] = f2bf(hv);
                }
            }
}

// ---------------- MFMA stage B: out[tok] += w * (h * Wd) ----------------
__global__ __launch_bounds__(256) void moe_stage_b_mfma(
        const unsigned short* __restrict__ h_buf, // [4160][768]
        const unsigned short* __restrict__ wdt,   // [8][2048][768]
        const int* __restrict__ counts,
        const int* __restrict__ offsets,
        const int* __restrict__ row_token,
        const float* __restrict__ row_w,
        float* __restrict__ out) {
    int e = blockIdx.x, mt = blockIdx.y, nt = blockIdx.z;
    int count = counts[e];
    int m0 = mt * 64;
    if (m0 >= count) return;
    int off = offsets[e];
    int n0 = nt * 64;
    int mcnt = min(64, count - m0);
    int tid = threadIdx.x;

    __shared__ __align__(16) unsigned short As[64 * 64];
    __shared__ __align__(16) unsigned short Bs[64 * 64];
    __shared__ int toks[64];
    __shared__ float rws[64];
    if (tid < 64) {
        int mm = min(tid, mcnt - 1);
        toks[tid] = row_token[off + m0 + mm];
        rws[tid] = row_w[off + m0 + mm];
    }

    int w = tid >> 6, l = tid & 63;
    int wr = w >> 1, wc = w & 1;
    int lr = l & 15, lh = l >> 4;
    int rA = w * 8 + (l >> 3);
    int cA = l & 7;

    const unsigned short* hb = h_buf + (size_t)(off + m0) * FINT;
    const unsigned short* wdE = wdt + (size_t)e * HID * FINT + (size_t)n0 * FINT;

    f32x4 acc[2][2] = {};

    for (int k0 = 0; k0 < FINT; k0 += 64) {
        #pragma unroll
        for (int i = 0; i < 2; ++i) {
            int row = 32 * i + rA;
            int sc = (cA ^ (row & 7)) << 3;
            char* dA = (char*)As + (size_t)(32 * i + w * 8) * 128;
            gl16(hb + (size_t)row * FINT + k0 + sc, dA);
            char* dB = (char*)Bs + (size_t)(32 * i + w * 8) * 128;
            gl16(wdE + (size_t)row * FINT + k0 + sc, dB);
        }
        __syncthreads();
        #pragma unroll
        for (int ks = 0; ks < 2; ++ks) {
            bf16x8 af[2], bb[2];
            #pragma unroll
            for (int mi = 0; mi < 2; ++mi) {
                int row = wr * 32 + mi * 16 + lr;
                int byte = row * 128 + ((ks * 64 + lh * 16) ^ ((row & 7) << 4));
                af[mi] = *(const bf16x8*)((const char*)As + byte);
            }
            #pragma unroll
            for (int ni = 0; ni < 2; ++ni) {
                int row = wc * 32 + ni * 16 + lr;
                int byte = row * 128 + ((ks * 64 + lh * 16) ^ ((row & 7) << 4));
                bb[ni] = *(const bf16x8*)((const char*)Bs + byte);
            }
            #pragma unroll
            for (int mi = 0; mi < 2; ++mi)
                #pragma unroll
                for (int ni = 0; ni < 2; ++ni)
                    acc[mi][ni] = __builtin_amdgcn_mfma_f32_16x16x32_bf16(af[mi], bb[ni], acc[mi][ni], 0, 0, 0);
        }
        __syncthreads();
    }

    #pragma unroll
    for (int mi = 0; mi < 2; ++mi)
        #pragma unroll
        for (int ni = 0; ni < 2; ++ni)
            #pragma unroll
            for (int j = 0; j < 4; ++j) {
                int row = wr * 32 + mi * 16 + lh * 4 + j;
                if (row < mcnt) {
                    int col = wc * 32 + ni * 16 + lr;
                    atomicAdd(&out[(size_t)toks[row] * HID + n0 + col],
                              rws[row] * acc[mi][ni][j]);
                }
            }
}

// ---------------- fp32 fallback (round-1 verified path) ----------------
#define MT 128
#define NT 64
#define KT 16

__global__ __launch_bounds__(256) void moe_stage_a_f32(
        const float* __restrict__ x,
        const float* __restrict__ w_gate,
        const float* __restrict__ w_up,
        const int* __restrict__ counts,
        const int* __restrict__ offsets,
        const int* __restrict__ row_token,
        float* __restrict__ h_buf) {
    int e = blockIdx.x, mt = blockIdx.y, nt = blockIdx.z;
    int count = counts[e];
    int m0 = mt * MT;
    if (m0 >= count) return;
    int off = offsets[e];
    int n0 = nt * NT;
    int mcnt = min(MT, count - m0);
    int tid = threadIdx.x;

    __shared__ float As[KT][MT];
    __shared__ float Bg[KT][NT];
    __shared__ float Bu[KT][NT];
    __shared__ int toks[MT];

    if (tid < MT) toks[tid] = row_token[off + m0 + (tid < mcnt ? tid : 0)];
    __syncthreads();

    int tm = tid >> 4, tn = tid & 15;
    float accg[8][4] = {{0}};
    float accu[8][4] = {{0}};

    const float* wg = w_gate + (size_t)e * HID * FINT + n0;
    const float* wu = w_up   + (size_t)e * HID * FINT + n0;

    for (int k0 = 0; k0 < HID; k0 += KT) {
        #pragma unroll
        for (int i = 0; i < 2; ++i) {
            int s = tid * 2 + i;
            int m = s >> 2;
            int kq = (s & 3) * 4;
            float4 v = *reinterpret_cast<const float4*>(&x[(size_t)toks[m] * HID + k0 + kq]);
            As[kq + 0][m] = v.x; As[kq + 1][m] = v.y;
            As[kq + 2][m] = v.z; As[kq + 3][m] = v.w;
        }
        {
            int k = tid >> 4;
            int nn = (tid & 15) * 4;
            *reinterpret_cast<float4*>(&Bg[k][nn]) =
                *reinterpret_cast<const float4*>(&wg[(size_t)(k0 + k) * FINT + nn]);
            *reinterpret_cast<float4*>(&Bu[k][nn]) =
                *reinterpret_cast<const float4*>(&wu[(size_t)(k0 + k) * FINT + nn]);
        }
        __syncthreads();
        #pragma unroll
        for (int k = 0; k < KT; ++k) {
            float a[8], bg[4], bu[4];
            *reinterpret_cast<float4*>(&a[0]) = *reinterpret_cast<const float4*>(&As[k][tm * 8 + 0]);
            *reinterpret_cast<float4*>(&a[4]) = *reinterpret_cast<const float4*>(&As[k][tm * 8 + 4]);
            *reinterpret_cast<float4*>(&bg[0]) = *reinterpret_cast<const float4*>(&Bg[k][tn * 4]);
            *reinterpret_cast<float4*>(&bu[0]) = *reinterpret_cast<const float4*>(&Bu[k][tn * 4]);
            #pragma unroll
            for (int i = 0; i < 8; ++i)
                #pragma unroll
                for (int j = 0; j < 4; ++j) {
                    accg[i][j] += a[i] * bg[j];
                    accu[i][j] += a[i] * bu[j];
                }
        }
        __syncthreads();
    }

    #pragma unroll
    for (int i = 0; i < 8; ++i) {
        int m = tm * 8 + i;
        if (m < mcnt) {
            float4 hv;
            float g, s;
            g = accg[i][0]; s = g / (1.f + expf(-g)); hv.x = s * accu[i][0];
            g = accg[i][1]; s = g / (1.f + expf(-g)); hv.y = s * accu[i][1];
            g = accg[i][2]; s = g / (1.f + expf(-g)); hv.z = s * accu[i][2];
            g = accg[i][3]; s = g / (1.f + expf(-g)); hv.w = s * accu[i][3];
            *reinterpret_cast<float4*>(&h_buf[(size_t)(off + m0 + m) * FINT + n0 + tn * 4]) = hv;
        }
    }
}

__global__ __launch_bounds__(256) void moe_stage_b_f32(
        const float* __restrict__ h_buf,
        const float* __restrict__ w_down,
        const int* __restrict__ counts,
        const int* __restrict__ offsets,
        const int* __restrict__ row_token,
        const float* __restrict__ row_w,
        float* __restrict__ out) {
    int e = blockIdx.x, mt = blockIdx.y, nt = blockIdx.z;
    int count = counts[e];
    int m0 = mt * MT;
    if (m0 >= count) return;
    int off = offsets[e];
    int n0 = nt * NT;
    int mcnt = min(MT, count - m0);
    int tid = threadIdx.x;

    __shared__ float As[KT][MT];
    __shared__ float Bs[KT][NT];
    __shared__ int toks[MT];
    __shared__ float rws[MT];

    if (tid < MT) {
        int m = tid < mcnt ? tid : 0;
        toks[tid] = row_token[off + m0 + m];
        rws[tid]  = row_w[off + m0 + m];
    }
    __syncthreads();

    int tm = tid >> 4, tn = tid & 15;
    float acc[8][4] = {{0}};

    const float* wd = w_down + (size_t)e * FINT * HID + n0;
    const float* ab = h_buf + (size_t)(off + m0) * FINT;

    for (int k0 = 0; k0 < FINT; k0 += KT) {
        #pragma unroll
        for (int i = 0; i < 2; ++i) {
            int s = tid * 2 + i;
            int m = s >> 2;
            int kq = (s & 3) * 4;
            int mm = m < mcnt ? m : 0;
            float4 v = *reinterpret_cast<const float4*>(&ab[(size_t)mm * FINT + k0 + kq]);
            As[kq + 0][m] = v.x; As[kq + 1][m] = v.y;
            As[kq + 2][m] = v.z; As[kq + 3][m] = v.w;
        }
        {
            int k = tid >> 4;
            int nn = (tid & 15) * 4;
            *reinterpret_cast<float4*>(&Bs[k][nn]) =
                *reinterpret_cast<const float4*>(&wd[(size_t)(k0 + k) * HID + nn]);
        }
        __syncthreads();
        #pragma unroll
        for (int k = 0; k < KT; ++k) {
            float a[8], b[4];
            *reinterpret_cast<float4*>(&a[0]) = *reinterpret_cast<const float4*>(&As[k][tm * 8 + 0]);
            *reinterpret_cast<float4*>(&a[4]) = *reinterpret_cast<const float4*>(&As[k][tm * 8 + 4]);
            *reinterpret_cast<float4*>(&b[0]) = *reinterpret_cast<const float4*>(&Bs[k][tn * 4]);
            #pragma unroll
            for (int i = 0; i < 8; ++i)
                #pragma unroll
                for (int j = 0; j < 4; ++j) acc[i][j] += a[i] * b[j];
        }
        __syncthreads();
    }

    #pragma unroll
    for (int i = 0; i < 8; ++i) {
        int m = tm * 8 + i;
        if (m < mcnt) {
            float w = rws[m];
            float* op = &out[(size_t)toks[m] * HID + n0 + tn * 4];
            #pragma unroll
            for (int j = 0; j < 4; ++j) atomicAdd(&op[j], w * acc[i][j]);
        }
    }
}

extern "C" void kernel_launch(void* const* d_in, const int* in_sizes, int n_in,
                              void* d_out, int out_size, void* d_ws, size_t ws_size,
                              hipStream_t stream) {
    const float* x       = (const float*)d_in[0];  // [2,1024,2048]
    const float* gate_w  = (const float*)d_in[1];  // [8,2048]
    const float* w_gate  = (const float*)d_in[2];  // [8,2048,768]
    const float* w_up    = (const float*)d_in[3];  // [8,2048,768]
    const float* w_down  = (const float*)d_in[4];  // [8,768,2048]
    float* out = (float*)d_out;                    // 2048*2048 out + 2048*8 logits

    char* ws = (char*)d_ws;
    int*   topk_idx  = (int*)  (ws + 0);
    float* topk_w    = (float*)(ws + 16384);
    int*   counts    = (int*)  (ws + 32768);
    int*   offsets   = (int*)  (ws + 32800);
    int*   row_token = (int*)  (ws + 33024);
    float* row_w     = (float*)(ws + 49408);
    int*   elist_t   = (int*)  (ws + 65792);
    float* elist_w   = (float*)(ws + 131328);

    float* logits_out = out + (size_t)NTOK * HID;

    hipMemsetAsync(out, 0, (size_t)NTOK * HID * sizeof(float), stream);

    moe_router_kernel<<<NTOK, 256, 0, stream>>>(x, gate_w, logits_out, topk_idx, topk_w);
    moe_build_kernel<<<1, 1024, 0, stream>>>(topk_idx, topk_w, counts, offsets,
                                             elist_t, elist_w, row_token, row_w);

    const size_t NEED = 90472704;
    if (ws_size >= NEED) {
        unsigned short* xb   = (unsigned short*)(ws + 196864);
        unsigned short* wg_t = (unsigned short*)(ws + 8585472);
        unsigned short* wu_t = (unsigned short*)(ws + 33751296);
        unsigned short* wd_t = (unsigned short*)(ws + 58917120);
        unsigned short* hb   = (unsigned short*)(ws + 84082944);

        cvt_x_kernel<<<2048, 256, 0, stream>>>(x, xb);
        dim3 gT1(HID / 64, FINT / 64, NEXP);   // w_gate/w_up: [2048][768] -> [768][2048]
        transpose_cvt_kernel<<<gT1, 256, 0, stream>>>(w_gate, wg_t, HID, FINT);
        transpose_cvt_kernel<<<gT1, 256, 0, stream>>>(w_up,   wu_t, HID, FINT);
        dim3 gT2(FINT / 64, HID / 64, NEXP);   // w_down: [768][2048] -> [2048][768]
        transpose_cvt_kernel<<<gT2, 256, 0, stream>>>(w_down, wd_t, FINT, HID);

        dim3 gridA(NEXP, NTOK / 64, FINT / 64);
        moe_stage_a_mfma<<<gridA, 256, 0, stream>>>(xb, wg_t, wu_t, counts, offsets,
                                                    row_token, hb);
        dim3 gridB(NEXP, NTOK / 64, HID / 64);
        moe_stage_b_mfma<<<gridB, 256, 0, stream>>>(hb, wd_t, counts, offsets,
                                                    row_token, row_w, out);
    } else {
        float* h_buf = (float*)(ws + 196864);
        dim3 gridA(NEXP, (NTOK + MT - 1) / MT, FINT / NT);
        moe_stage_a_f32<<<gridA, 256, 0, stream>>>(x, w_gate, w_up, counts, offsets,
                                                   row_token, h_buf);
        dim3 gridB(NEXP, (NTOK + MT - 1) / MT, HID / NT);
        moe_stage_b_f32<<<gridB, 256, 0, stream>>>(h_buf, w_down, counts, offsets,
                                                   row_token, row_w, out);
    }
}

// Round 3
// 192.299 us; speedup vs baseline: 4.8314x; 1.0194x over previous
//
#include <hip/hip_runtime.h>
#include <hip/hip_bf16.h>
#include <math.h>

#define NTOK 2048
#define HID 2048
#define NEXP 8
#define FINT 768
#define TOPK 2

typedef __attribute__((ext_vector_type(8))) short bf16x8;
typedef __attribute__((ext_vector_type(4))) float f32x4;

static __device__ __forceinline__ unsigned short f2bf(float f) {
    union { float f; unsigned u; } v; v.f = f;
    unsigned r = v.u + 0x7fffu + ((v.u >> 16) & 1u);
    return (unsigned short)(r >> 16);
}

static __device__ __forceinline__ void gl16(const void* g, void* l) {
    __builtin_amdgcn_global_load_lds(
        (const __attribute__((address_space(1))) unsigned int*)g,
        (__attribute__((address_space(3))) unsigned int*)(uintptr_t)l,
        16, 0, 0);
}

// ---------------- workspace layout (bytes) ----------------
// 0       : topk_idx  int[4096]
// 16384   : topk_w    f32[4096]
// 32768   : counts    int[8]
// 32800   : offsets   int[8]
// 33024   : row_token int[4096]
// 49408   : row_w     f32[4096]
// 65792   : elist_t   int[8*2048]
// 131328  : elist_w   f32[8*2048]
// bf16 path:
// 196864  : x_bf16    [2048][2048]        8388608
// 8585472 : wg_t      [8][768][2048] bf16 25165824
// 33751296: wu_t      [8][768][2048] bf16 25165824
// 58917120: wd_t      [8][2048][768] bf16 25165824
// 84082944: h_buf     [4224][768]    bf16 6488064   -> end 90571008

// ---------------- fused router + x bf16 cast ----------------
__global__ __launch_bounds__(256) void moe_router_cvt(
        const float* __restrict__ x,
        const float* __restrict__ gw,
        float* __restrict__ logits_out,
        int* __restrict__ topk_idx,
        float* __restrict__ topk_w,
        unsigned short* __restrict__ xb) {
    int w = threadIdx.x >> 6, l = threadIdx.x & 63;
    int t = blockIdx.x * 4 + w;
    const float4* xr = (const float4*)(x + (size_t)t * HID);
    unsigned short* xbr = xb + (size_t)t * HID;
    float4 v[8];
    #pragma unroll
    for (int i = 0; i < 8; ++i) v[i] = xr[i * 64 + l];
    #pragma unroll
    for (int i = 0; i < 8; ++i)
        *(ushort4*)&xbr[(i * 64 + l) * 4] =
            make_ushort4(f2bf(v[i].x), f2bf(v[i].y), f2bf(v[i].z), f2bf(v[i].w));
    float acc[NEXP];
    #pragma unroll
    for (int e = 0; e < NEXP; ++e) {
        const float4* gr = (const float4*)(gw + (size_t)e * HID);
        float a = 0.f;
        #pragma unroll
        for (int i = 0; i < 8; ++i) {
            float4 g = gr[i * 64 + l];
            a += v[i].x * g.x + v[i].y * g.y + v[i].z * g.z + v[i].w * g.w;
        }
        acc[e] = a;
    }
    #pragma unroll
    for (int off = 32; off > 0; off >>= 1)
        #pragma unroll
        for (int e = 0; e < NEXP; ++e) acc[e] += __shfl_xor(acc[e], off);
    if (l == 0) {
        float m = -1e30f;
        #pragma unroll
        for (int i = 0; i < NEXP; ++i) m = fmaxf(m, acc[i]);
        float p[NEXP];
        #pragma unroll
        for (int i = 0; i < NEXP; ++i) p[i] = expf(acc[i] - m);
        int i0 = 0;
        #pragma unroll
        for (int i = 1; i < NEXP; ++i) if (p[i] > p[i0]) i0 = i;
        int i1 = (i0 == 0) ? 1 : 0;
        #pragma unroll
        for (int i = 0; i < NEXP; ++i) if (i != i0 && p[i] > p[i1]) i1 = i;
        float w0 = p[i0], w1 = p[i1], sw = w0 + w1;
        topk_idx[t * 2 + 0] = i0;
        topk_idx[t * 2 + 1] = i1;
        topk_w[t * 2 + 0] = w0 / sw;
        topk_w[t * 2 + 1] = w1 / sw;
        #pragma unroll
        for (int i = 0; i < NEXP; ++i) logits_out[(size_t)t * NEXP + i] = acc[i];
    }
}

__global__ void moe_build_kernel(const int* __restrict__ topk_idx,
                                 const float* __restrict__ topk_w,
                                 int* __restrict__ counts,
                                 int* __restrict__ offsets,
                                 int* __restrict__ elist_t,
                                 float* __restrict__ elist_w,
                                 int* __restrict__ row_token,
                                 float* __restrict__ row_w) {
    __shared__ int scnt[NEXP];
    __shared__ int soff[NEXP];
    int tid = threadIdx.x; // 1024
    if (tid < NEXP) scnt[tid] = 0;
    __syncthreads();
    for (int t = tid; t < NTOK; t += 1024) {
        #pragma unroll
        for (int k = 0; k < TOPK; ++k) {
            int e = topk_idx[t * 2 + k];
            float w = topk_w[t * 2 + k];
            int slot = atomicAdd(&scnt[e], 1);
            elist_t[e * NTOK + slot] = t;
            elist_w[e * NTOK + slot] = w;
        }
    }
    __syncthreads();
    if (tid == 0) {
        int o = 0;
        for (int e = 0; e < NEXP; ++e) {
            soff[e] = o; offsets[e] = o; counts[e] = scnt[e]; o += scnt[e];
        }
    }
    __syncthreads();
    for (int e = 0; e < NEXP; ++e) {
        int c = scnt[e], o = soff[e];
        for (int s = tid; s < c; s += 1024) {
            row_token[o + s] = elist_t[e * NTOK + s];
            row_w[o + s]     = elist_w[e * NTOK + s];
        }
    }
}

// ---------------- single-launch transpose+cvt of all three weights ----------------
// [e][R][C] f32 -> [e][C][R] bf16
__global__ __launch_bounds__(256) void transpose_cvt_all(
        const float* __restrict__ wg, const float* __restrict__ wu,
        const float* __restrict__ wd,
        unsigned short* __restrict__ wgt, unsigned short* __restrict__ wut,
        unsigned short* __restrict__ wdt) {
    int e = blockIdx.y;
    int idx = blockIdx.x;   // 0..1151
    const float* src; unsigned short* dst; int R, C, tr, tc;
    if (idx < 384)      { src = wg; dst = wgt; R = HID;  C = FINT; tr = idx / 12; tc = idx % 12; }
    else if (idx < 768) { idx -= 384; src = wu; dst = wut; R = HID;  C = FINT; tr = idx / 12; tc = idx % 12; }
    else                { idx -= 768; src = wd; dst = wdt; R = FINT; C = HID;  tr = idx / 32; tc = idx % 32; }
    int r0 = tr * 64, c0 = tc * 64;
    src += (size_t)e * R * C;
    dst += (size_t)e * R * C;
    __shared__ unsigned short tile[64][68];
    int tid = threadIdx.x;
    {
        int row = tid >> 2, cq = (tid & 3) * 16;
        #pragma unroll
        for (int i = 0; i < 4; ++i) {
            float4 v = *(const float4*)&src[(size_t)(r0 + row) * C + c0 + cq + i * 4];
            *(ushort4*)&tile[row][cq + i * 4] =
                make_ushort4(f2bf(v.x), f2bf(v.y), f2bf(v.z), f2bf(v.w));
        }
    }
    __syncthreads();
    {
        int c = tid >> 2, rq = (tid & 3) * 16;
        #pragma unroll
        for (int i = 0; i < 4; ++i) {
            ushort4 o = make_ushort4(tile[rq + i * 4 + 0][c], tile[rq + i * 4 + 1][c],
                                     tile[rq + i * 4 + 2][c], tile[rq + i * 4 + 3][c]);
            *(ushort4*)&dst[(size_t)(c0 + c) * R + r0 + rq + i * 4] = o;
        }
    }
}

// ---------------- MFMA stage A: h = silu(x*Wg) * (x*Wu) ----------------
// 128 token-rows x 64 inter-cols (both g and u), BK=64, 4 waves (2x2).
__global__ __launch_bounds__(256) void moe_stage_a_mfma(
        const unsigned short* __restrict__ xb,    // [2048][2048]
        const unsigned short* __restrict__ wgt,   // [8][768][2048]
        const unsigned short* __restrict__ wut,   // [8][768][2048]
        const int* __restrict__ counts,
        const int* __restrict__ offsets,
        const int* __restrict__ row_token,
        unsigned short* __restrict__ h_buf) {     // [4224][768]
    int e = blockIdx.x, mt = blockIdx.y, nt = blockIdx.z;
    int count = counts[e];
    int m0 = mt * 128;
    if (m0 >= count) return;
    int off = offsets[e];
    int n0 = nt * 64;
    int mcnt = min(128, count - m0);
    int tid = threadIdx.x;

    __shared__ __align__(16) unsigned short As[128 * 64];  // 16 KB, rows of 128B
    __shared__ __align__(16) unsigned short Bg[64 * 64];   // 8 KB
    __shared__ __align__(16) unsigned short Bu[64 * 64];   // 8 KB
    __shared__ int toks[128];
    if (tid < 128) toks[tid] = row_token[off + m0 + min(tid, mcnt - 1)];
    __syncthreads();

    int w = tid >> 6, l = tid & 63;
    int wr = w >> 1, wc = w & 1;
    int lr = l & 15, lh = l >> 4;
    int wbase = (tid & 192) * 16;    // wave-uniform LDS byte base step

    const unsigned short* wgE = wgt + (size_t)e * FINT * HID + (size_t)n0 * HID;
    const unsigned short* wuE = wut + (size_t)e * FINT * HID + (size_t)n0 * HID;

    f32x4 gacc[4][2] = {};
    f32x4 uacc[4][2] = {};

    for (int k0 = 0; k0 < HID; k0 += 64) {
        #pragma unroll
        for (int i = 0; i < 4; ++i) {
            int s = i * 256 + tid;            // chunk index this lane covers
            int row = s >> 3, c = s & 7;
            int sc = (c ^ (row & 7)) << 3;    // pre-swizzled source elem offset
            gl16(xb + (size_t)toks[row] * HID + k0 + sc,
                 (char*)As + i * 4096 + wbase);
        }
        #pragma unroll
        for (int i = 0; i < 2; ++i) {
            int s = i * 256 + tid;
            int row = s >> 3, c = s & 7;
            int sc = (c ^ (row & 7)) << 3;
            gl16(wgE + (size_t)row * HID + k0 + sc, (char*)Bg + i * 4096 + wbase);
            gl16(wuE + (size_t)row * HID + k0 + sc, (char*)Bu + i * 4096 + wbase);
        }
        __syncthreads();
        #pragma unroll
        for (int ks = 0; ks < 2; ++ks) {
            bf16x8 af[4], bg[2], bu[2];
            #pragma unroll
            for (int mi = 0; mi < 4; ++mi) {
                int row = wr * 64 + mi * 16 + lr;
                int byte = row * 128 + ((ks * 64 + lh * 16) ^ ((row & 7) << 4));
                af[mi] = *(const bf16x8*)((const char*)As + byte);
            }
            #pragma unroll
            for (int ni = 0; ni < 2; ++ni) {
                int row = wc * 32 + ni * 16 + lr;
                int byte = row * 128 + ((ks * 64 + lh * 16) ^ ((row & 7) << 4));
                bg[ni] = *(const bf16x8*)((const char*)Bg + byte);
                bu[ni] = *(const bf16x8*)((const char*)Bu + byte);
            }
            #pragma unroll
            for (int mi = 0; mi < 4; ++mi)
                #pragma unroll
                for (int ni = 0; ni < 2; ++ni) {
                    gacc[mi][ni] = __builtin_amdgcn_mfma_f32_16x16x32_bf16(af[mi], bg[ni], gacc[mi][ni], 0, 0, 0);
                    uacc[mi][ni] = __builtin_amdgcn_mfma_f32_16x16x32_bf16(af[mi], bu[ni], uacc[mi][ni], 0, 0, 0);
                }
        }
        __syncthreads();
    }

    #pragma unroll
    for (int mi = 0; mi < 4; ++mi)
        #pragma unroll
        for (int ni = 0; ni < 2; ++ni)
            #pragma unroll
            for (int j = 0; j < 4; ++j) {
                int row = wr * 64 + mi * 16 + lh * 4 + j;
                if (row < mcnt) {
                    int col = wc * 32 + ni * 16 + lr;
                    float g = gacc[mi][ni][j], u = uacc[mi][ni][j];
                    float hv = g / (1.f + expf(-g)) * u;
                    h_buf[(size_t)(off + m0 + row) * FINT + n0 + col] = f2bf(hv);
                }
            }
}

// ---------------- MFMA stage B: out[tok] += w * (h * Wd) ----------------
// m97 structure: 128x128 tile, BK=64, 4 waves (2x2), acc[4][4] per wave.
__global__ __launch_bounds__(256) void moe_stage_b_mfma(
        const unsigned short* __restrict__ h_buf, // [4224][768]
        const unsigned short* __restrict__ wdt,   // [8][2048][768]
        const int* __restrict__ counts,
        const int* __restrict__ offsets,
        const int* __restrict__ row_token,
        const float* __restrict__ row_w,
        float* __restrict__ out) {
    int e = blockIdx.x, mt = blockIdx.y, nt = blockIdx.z;
    int count = counts[e];
    int m0 = mt * 128;
    if (m0 >= count) return;
    int off = offsets[e];
    int n0 = nt * 128;
    int mcnt = min(128, count - m0);
    int tid = threadIdx.x;

    __shared__ __align__(16) unsigned short As[128 * 64];  // 16 KB
    __shared__ __align__(16) unsigned short Bs[128 * 64];  // 16 KB
    __shared__ int toks[128];
    __shared__ float rws[128];
    if (tid < 128) {
        int mm = min(tid, mcnt - 1);
        toks[tid] = row_token[off + m0 + mm];
        rws[tid] = row_w[off + m0 + mm];
    }

    int w = tid >> 6, l = tid & 63;
    int wr = w >> 1, wc = w & 1;
    int lr = l & 15, lh = l >> 4;
    int wbase = (tid & 192) * 16;

    const unsigned short* hb = h_buf + (size_t)(off + m0) * FINT;
    const unsigned short* wdE = wdt + (size_t)e * HID * FINT + (size_t)n0 * FINT;

    f32x4 acc[4][4] = {};

    for (int k0 = 0; k0 < FINT; k0 += 64) {
        #pragma unroll
        for (int i = 0; i < 4; ++i) {
            int s = i * 256 + tid;
            int row = s >> 3, c = s & 7;
            int sc = (c ^ (row & 7)) << 3;
            gl16(hb + (size_t)row * FINT + k0 + sc, (char*)As + i * 4096 + wbase);
            gl16(wdE + (size_t)row * FINT + k0 + sc, (char*)Bs + i * 4096 + wbase);
        }
        __syncthreads();
        #pragma unroll
        for (int ks = 0; ks < 2; ++ks) {
            bf16x8 af[4], bf[4];
            #pragma unroll
            for (int mi = 0; mi < 4; ++mi) {
                int row = wr * 64 + mi * 16 + lr;
                int byte = row * 128 + ((ks * 64 + lh * 16) ^ ((row & 7) << 4));
                af[mi] = *(const bf16x8*)((const char*)As + byte);
            }
            #pragma unroll
            for (int ni = 0; ni < 4; ++ni) {
                int row = wc * 64 + ni * 16 + lr;
                int byte = row * 128 + ((ks * 64 + lh * 16) ^ ((row & 7) << 4));
                bf[ni] = *(const bf16x8*)((const char*)Bs + byte);
            }
            #pragma unroll
            for (int mi = 0; mi < 4; ++mi)
                #pragma unroll
                for (int ni = 0; ni < 4; ++ni)
                    acc[mi][ni] = __builtin_amdgcn_mfma_f32_16x16x32_bf16(af[mi], bf[ni], acc[mi][ni], 0, 0, 0);
        }
        __syncthreads();
    }

    #pragma unroll
    for (int mi = 0; mi < 4; ++mi)
        #pragma unroll
        for (int ni = 0; ni < 4; ++ni)
            #pragma unroll
            for (int j = 0; j < 4; ++j) {
                int row = wr * 64 + mi * 16 + lh * 4 + j;
                if (row < mcnt) {
                    int col = n0 + wc * 64 + ni * 16 + lr;
                    atomicAdd(&out[(size_t)toks[row] * HID + col],
                              rws[row] * acc[mi][ni][j]);
                }
            }
}

// ---------------- fp32 fallback (verified round-1 path) ----------------
#define MT 128
#define NT 64
#define KT 16

__global__ __launch_bounds__(256) void moe_stage_a_f32(
        const float* __restrict__ x,
        const float* __restrict__ w_gate,
        const float* __restrict__ w_up,
        const int* __restrict__ counts,
        const int* __restrict__ offsets,
        const int* __restrict__ row_token,
        float* __restrict__ h_buf) {
    int e = blockIdx.x, mt = blockIdx.y, nt = blockIdx.z;
    int count = counts[e];
    int m0 = mt * MT;
    if (m0 >= count) return;
    int off = offsets[e];
    int n0 = nt * NT;
    int mcnt = min(MT, count - m0);
    int tid = threadIdx.x;

    __shared__ float As[KT][MT];
    __shared__ float Bg[KT][NT];
    __shared__ float Bu[KT][NT];
    __shared__ int toks[MT];

    if (tid < MT) toks[tid] = row_token[off + m0 + (tid < mcnt ? tid : 0)];
    __syncthreads();

    int tm = tid >> 4, tn = tid & 15;
    float accg[8][4] = {{0}};
    float accu[8][4] = {{0}};

    const float* wg = w_gate + (size_t)e * HID * FINT + n0;
    const float* wu = w_up   + (size_t)e * HID * FINT + n0;

    for (int k0 = 0; k0 < HID; k0 += KT) {
        #pragma unroll
        for (int i = 0; i < 2; ++i) {
            int s = tid * 2 + i;
            int m = s >> 2;
            int kq = (s & 3) * 4;
            float4 v = *reinterpret_cast<const float4*>(&x[(size_t)toks[m] * HID + k0 + kq]);
            As[kq + 0][m] = v.x; As[kq + 1][m] = v.y;
            As[kq + 2][m] = v.z; As[kq + 3][m] = v.w;
        }
        {
            int k = tid >> 4;
            int nn = (tid & 15) * 4;
            *reinterpret_cast<float4*>(&Bg[k][nn]) =
                *reinterpret_cast<const float4*>(&wg[(size_t)(k0 + k) * FINT + nn]);
            *reinterpret_cast<float4*>(&Bu[k][nn]) =
                *reinterpret_cast<const float4*>(&wu[(size_t)(k0 + k) * FINT + nn]);
        }
        __syncthreads();
        #pragma unroll
        for (int k = 0; k < KT; ++k) {
            float a[8], bg[4], bu[4];
            *reinterpret_cast<float4*>(&a[0]) = *reinterpret_cast<const float4*>(&As[k][tm * 8 + 0]);
            *reinterpret_cast<float4*>(&a[4]) = *reinterpret_cast<const float4*>(&As[k][tm * 8 + 4]);
            *reinterpret_cast<float4*>(&bg[0]) = *reinterpret_cast<const float4*>(&Bg[k][tn * 4]);
            *reinterpret_cast<float4*>(&bu[0]) = *reinterpret_cast<const float4*>(&Bu[k][tn * 4]);
            #pragma unroll
            for (int i = 0; i < 8; ++i)
                #pragma unroll
                for (int j = 0; j < 4; ++j) {
                    accg[i][j] += a[i] * bg[j];
                    accu[i][j] += a[i] * bu[j];
                }
        }
        __syncthreads();
    }

    #pragma unroll
    for (int i = 0; i < 8; ++i) {
        int m = tm * 8 + i;
        if (m < mcnt) {
            float4 hv;
            float g, s;
            g = accg[i][0]; s = g / (1.f + expf(-g)); hv.x = s * accu[i][0];
            g = accg[i][1]; s = g / (1.f + expf(-g)); hv.y = s * accu[i][1];
            g = accg[i][2]; s = g / (1.f + expf(-g)); hv.z = s * accu[i][2];
            g = accg[i][3]; s = g / (1.f + expf(-g)); hv.w = s * accu[i][3];
            *reinterpret_cast<float4*>(&h_buf[(size_t)(off + m0 + m) * FINT + n0 + tn * 4]) = hv;
        }
    }
}

__global__ __launch_bounds__(256) void moe_stage_b_f32(
        const float* __restrict__ h_buf,
        const float* __restrict__ w_down,
        const int* __restrict__ counts,
        const int* __restrict__ offsets,
        const int* __restrict__ row_token,
        const float* __restrict__ row_w,
        float* __restrict__ out) {
    int e = blockIdx.x, mt = blockIdx.y, nt = blockIdx.z;
    int count = counts[e];
    int m0 = mt * MT;
    if (m0 >= count) return;
    int off = offsets[e];
    int n0 = nt * NT;
    int mcnt = min(MT, count - m0);
    int tid = threadIdx.x;

    __shared__ float As[KT][MT];
    __shared__ float Bs[KT][NT];
    __shared__ int toks[MT];
    __shared__ float rws[MT];

    if (tid < MT) {
        int m = tid < mcnt ? tid : 0;
        toks[tid] = row_token[off + m0 + m];
        rws[tid]  = row_w[off + m0 + m];
    }
    __syncthreads();

    int tm = tid >> 4, tn = tid & 15;
    float acc[8][4] = {{0}};

    const float* wd = w_down + (size_t)e * FINT * HID + n0;
    const float* ab = h_buf + (size_t)(off + m0) * FINT;

    for (int k0 = 0; k0 < FINT; k0 += KT) {
        #pragma unroll
        for (int i = 0; i < 2; ++i) {
            int s = tid * 2 + i;
            int m = s >> 2;
            int kq = (s & 3) * 4;
            int mm = m < mcnt ? m : 0;
            float4 v = *reinterpret_cast<const float4*>(&ab[(size_t)mm * FINT + k0 + kq]);
            As[kq + 0][m] = v.x; As[kq + 1][m] = v.y;
            As[kq + 2][m] = v.z; As[kq + 3][m] = v.w;
        }
        {
            int k = tid >> 4;
            int nn = (tid & 15) * 4;
            *reinterpret_cast<float4*>(&Bs[k][nn]) =
                *reinterpret_cast<const float4*>(&wd[(size_t)(k0 + k) * HID + nn]);
        }
        __syncthreads();
        #pragma unroll
        for (int k = 0; k < KT; ++k) {
            float a[8], b[4];
            *reinterpret_cast<float4*>(&a[0]) = *reinterpret_cast<const float4*>(&As[k][tm * 8 + 0]);
            *reinterpret_cast<float4*>(&a[4]) = *reinterpret_cast<const float4*>(&As[k][tm * 8 + 4]);
            *reinterpret_cast<float4*>(&b[0]) = *reinterpret_cast<const float4*>(&Bs[k][tn * 4]);
            #pragma unroll
            for (int i = 0; i < 8; ++i)
                #pragma unroll
                for (int j = 0; j < 4; ++j) acc[i][j] += a[i] * b[j];
        }
        __syncthreads();
    }

    #pragma unroll
    for (int i = 0; i < 8; ++i) {
        int m = tm * 8 + i;
        if (m < mcnt) {
            float w = rws[m];
            float* op = &out[(size_t)toks[m] * HID + n0 + tn * 4];
            #pragma unroll
            for (int j = 0; j < 4; ++j) atomicAdd(&op[j], w * acc[i][j]);
        }
    }
}

extern "C" void kernel_launch(void* const* d_in, const int* in_sizes, int n_in,
                              void* d_out, int out_size, void* d_ws, size_t ws_size,
                              hipStream_t stream) {
    const float* x       = (const float*)d_in[0];  // [2,1024,2048]
    const float* gate_w  = (const float*)d_in[1];  // [8,2048]
    const float* w_gate  = (const float*)d_in[2];  // [8,2048,768]
    const float* w_up    = (const float*)d_in[3];  // [8,2048,768]
    const float* w_down  = (const float*)d_in[4];  // [8,768,2048]
    float* out = (float*)d_out;                    // 2048*2048 out + 2048*8 logits

    char* ws = (char*)d_ws;
    int*   topk_idx  = (int*)  (ws + 0);
    float* topk_w    = (float*)(ws + 16384);
    int*   counts    = (int*)  (ws + 32768);
    int*   offsets   = (int*)  (ws + 32800);
    int*   row_token = (int*)  (ws + 33024);
    float* row_w     = (float*)(ws + 49408);
    int*   elist_t   = (int*)  (ws + 65792);
    float* elist_w   = (float*)(ws + 131328);

    float* logits_out = out + (size_t)NTOK * HID;

    hipMemsetAsync(out, 0, (size_t)NTOK * HID * sizeof(float), stream);

    const size_t NEED = 90571008;
    if (ws_size >= NEED) {
        unsigned short* xb   = (unsigned short*)(ws + 196864);
        unsigned short* wg_t = (unsigned short*)(ws + 8585472);
        unsigned short* wu_t = (unsigned short*)(ws + 33751296);
        unsigned short* wd_t = (unsigned short*)(ws + 58917120);
        unsigned short* hb   = (unsigned short*)(ws + 84082944);

        moe_router_cvt<<<NTOK / 4, 256, 0, stream>>>(x, gate_w, logits_out,
                                                     topk_idx, topk_w, xb);
        moe_build_kernel<<<1, 1024, 0, stream>>>(topk_idx, topk_w, counts, offsets,
                                                 elist_t, elist_w, row_token, row_w);
        dim3 gT(1152, NEXP);
        transpose_cvt_all<<<gT, 256, 0, stream>>>(w_gate, w_up, w_down,
                                                  wg_t, wu_t, wd_t);

        dim3 gridA(NEXP, NTOK / 128, FINT / 64);
        moe_stage_a_mfma<<<gridA, 256, 0, stream>>>(xb, wg_t, wu_t, counts, offsets,
                                                    row_token, hb);
        dim3 gridB(NEXP, NTOK / 128, HID / 128);
        moe_stage_b_mfma<<<gridB, 256, 0, stream>>>(hb, wd_t, counts, offsets,
                                                    row_token, row_w, out);
    } else {
        // fp32 fallback
        {
            // router without fused cvt: reuse fused kernel but write xb into a
            // small scratch that must exist; fall back to simple router loop.
            // (ws always has >=196864+8MB in practice; this path is for safety.)
        }
        float* h_buf = (float*)(ws + 196864);
        // minimal router via fused kernel writing bf16 x into h_buf area is
        // unsafe; use build-only path with a tiny router kernel:
        // For safety, run the fused router but point xb at h_buf (16MB free
        // region exists since fallback only needs 12.6MB starting at 196864;
        // overlap is fine because h_buf is written later).
        moe_router_cvt<<<NTOK / 4, 256, 0, stream>>>(x, gate_w, logits_out,
                                                     topk_idx, topk_w,
                                                     (unsigned short*)(ws + 196864));
        moe_build_kernel<<<1, 1024, 0, stream>>>(topk_idx, topk_w, counts, offsets,
                                                 elist_t, elist_w, row_token, row_w);
        dim3 gridA(NEXP, (NTOK + MT - 1) / MT, FINT / NT);
        moe_stage_a_f32<<<gridA, 256, 0, stream>>>(x, w_gate, w_up, counts, offsets,
                                                   row_token, h_buf);
        dim3 gridB(NEXP, (NTOK + MT - 1) / MT, HID / NT);
        moe_stage_b_f32<<<gridB, 256, 0, stream>>>(h_buf, w_down, counts, offsets,
                                                   row_token, row_w, out);
    }
}

// Round 4
// 162.101 us; speedup vs baseline: 5.7314x; 1.1863x over previous
//
#include <hip/hip_runtime.h>
#include <hip/hip_bf16.h>
#include <math.h>

#define NTOK 2048
#define HID 2048
#define NEXP 8
#define FINT 768
#define TOPK 2

typedef __attribute__((ext_vector_type(8))) short bf16x8;
typedef __attribute__((ext_vector_type(4))) float f32x4;

static __device__ __forceinline__ unsigned short f2bf(float f) {
    union { float f; unsigned u; } v; v.f = f;
    unsigned r = v.u + 0x7fffu + ((v.u >> 16) & 1u);
    return (unsigned short)(r >> 16);
}

static __device__ __forceinline__ void gl16(const void* g, void* l) {
    __builtin_amdgcn_global_load_lds(
        (const __attribute__((address_space(1))) unsigned int*)g,
        (__attribute__((address_space(3))) unsigned int*)(uintptr_t)l,
        16, 0, 0);
}

// ---------------- workspace layout (bytes) ----------------
// 0       : topk_idx  int[4096]
// 16384   : topk_w    f32[4096]
// 32768   : counts    int[8]
// 32800   : offsets   int[8]
// 33024   : row_token int[4096]
// 49408   : row_w     f32[4096]
// 65792   : elist_t   int[8*2048]
// 131328  : elist_w   f32[8*2048]
// 196864  : x_bf16    [2048][2048]        8388608
// 8585472 : wg_t      [8][768][2048] bf16 25165824
// 33751296: wu_t      [8][768][2048] bf16 25165824
// 58917120: wd_t      [8][2048][768] bf16 25165824
// 84082944: h_buf     [4224][768]    bf16 6488064   -> end 90571008

// ---------------- fused router + x bf16 cast ----------------
__global__ __launch_bounds__(256) void moe_router_cvt(
        const float* __restrict__ x,
        const float* __restrict__ gw,
        float* __restrict__ logits_out,
        int* __restrict__ topk_idx,
        float* __restrict__ topk_w,
        unsigned short* __restrict__ xb) {
    int w = threadIdx.x >> 6, l = threadIdx.x & 63;
    int t = blockIdx.x * 4 + w;
    const float4* xr = (const float4*)(x + (size_t)t * HID);
    unsigned short* xbr = xb + (size_t)t * HID;
    float4 v[8];
    #pragma unroll
    for (int i = 0; i < 8; ++i) v[i] = xr[i * 64 + l];
    #pragma unroll
    for (int i = 0; i < 8; ++i)
        *(ushort4*)&xbr[(i * 64 + l) * 4] =
            make_ushort4(f2bf(v[i].x), f2bf(v[i].y), f2bf(v[i].z), f2bf(v[i].w));
    float acc[NEXP];
    #pragma unroll
    for (int e = 0; e < NEXP; ++e) {
        const float4* gr = (const float4*)(gw + (size_t)e * HID);
        float a = 0.f;
        #pragma unroll
        for (int i = 0; i < 8; ++i) {
            float4 g = gr[i * 64 + l];
            a += v[i].x * g.x + v[i].y * g.y + v[i].z * g.z + v[i].w * g.w;
        }
        acc[e] = a;
    }
    #pragma unroll
    for (int off = 32; off > 0; off >>= 1)
        #pragma unroll
        for (int e = 0; e < NEXP; ++e) acc[e] += __shfl_xor(acc[e], off);
    if (l == 0) {
        float m = -1e30f;
        #pragma unroll
        for (int i = 0; i < NEXP; ++i) m = fmaxf(m, acc[i]);
        float p[NEXP];
        #pragma unroll
        for (int i = 0; i < NEXP; ++i) p[i] = expf(acc[i] - m);
        int i0 = 0;
        #pragma unroll
        for (int i = 1; i < NEXP; ++i) if (p[i] > p[i0]) i0 = i;
        int i1 = (i0 == 0) ? 1 : 0;
        #pragma unroll
        for (int i = 0; i < NEXP; ++i) if (i != i0 && p[i] > p[i1]) i1 = i;
        float w0 = p[i0], w1 = p[i1], sw = w0 + w1;
        topk_idx[t * 2 + 0] = i0;
        topk_idx[t * 2 + 1] = i1;
        topk_w[t * 2 + 0] = w0 / sw;
        topk_w[t * 2 + 1] = w1 / sw;
        #pragma unroll
        for (int i = 0; i < NEXP; ++i) logits_out[(size_t)t * NEXP + i] = acc[i];
    }
}

__global__ void moe_build_kernel(const int* __restrict__ topk_idx,
                                 const float* __restrict__ topk_w,
                                 int* __restrict__ counts,
                                 int* __restrict__ offsets,
                                 int* __restrict__ elist_t,
                                 float* __restrict__ elist_w,
                                 int* __restrict__ row_token,
                                 float* __restrict__ row_w) {
    __shared__ int scnt[NEXP];
    __shared__ int soff[NEXP];
    int tid = threadIdx.x; // 1024
    if (tid < NEXP) scnt[tid] = 0;
    __syncthreads();
    for (int t = tid; t < NTOK; t += 1024) {
        #pragma unroll
        for (int k = 0; k < TOPK; ++k) {
            int e = topk_idx[t * 2 + k];
            float w = topk_w[t * 2 + k];
            int slot = atomicAdd(&scnt[e], 1);
            elist_t[e * NTOK + slot] = t;
            elist_w[e * NTOK + slot] = w;
        }
    }
    __syncthreads();
    if (tid == 0) {
        int o = 0;
        for (int e = 0; e < NEXP; ++e) {
            soff[e] = o; offsets[e] = o; counts[e] = scnt[e]; o += scnt[e];
        }
    }
    __syncthreads();
    for (int e = 0; e < NEXP; ++e) {
        int c = scnt[e], o = soff[e];
        for (int s = tid; s < c; s += 1024) {
            row_token[o + s] = elist_t[e * NTOK + s];
            row_w[o + s]     = elist_w[e * NTOK + s];
        }
    }
}

// ---------------- single-launch transpose+cvt of all three weights ----------------
// [e][R][C] f32 -> [e][C][R] bf16
__global__ __launch_bounds__(256) void transpose_cvt_all(
        const float* __restrict__ wg, const float* __restrict__ wu,
        const float* __restrict__ wd,
        unsigned short* __restrict__ wgt, unsigned short* __restrict__ wut,
        unsigned short* __restrict__ wdt) {
    int e = blockIdx.y;
    int idx = blockIdx.x;   // 0..1151
    const float* src; unsigned short* dst; int R, C, tr, tc;
    if (idx < 384)      { src = wg; dst = wgt; R = HID;  C = FINT; tr = idx / 12; tc = idx % 12; }
    else if (idx < 768) { idx -= 384; src = wu; dst = wut; R = HID;  C = FINT; tr = idx / 12; tc = idx % 12; }
    else                { idx -= 768; src = wd; dst = wdt; R = FINT; C = HID;  tr = idx / 32; tc = idx % 32; }
    int r0 = tr * 64, c0 = tc * 64;
    src += (size_t)e * R * C;
    dst += (size_t)e * R * C;
    __shared__ unsigned short tile[64][68];
    int tid = threadIdx.x;
    {
        int row = tid >> 2, cq = (tid & 3) * 16;
        #pragma unroll
        for (int i = 0; i < 4; ++i) {
            float4 v = *(const float4*)&src[(size_t)(r0 + row) * C + c0 + cq + i * 4];
            *(ushort4*)&tile[row][cq + i * 4] =
                make_ushort4(f2bf(v.x), f2bf(v.y), f2bf(v.z), f2bf(v.w));
        }
    }
    __syncthreads();
    {
        int c = tid >> 2, rq = (tid & 3) * 16;
        #pragma unroll
        for (int i = 0; i < 4; ++i) {
            ushort4 o = make_ushort4(tile[rq + i * 4 + 0][c], tile[rq + i * 4 + 1][c],
                                     tile[rq + i * 4 + 2][c], tile[rq + i * 4 + 3][c]);
            *(ushort4*)&dst[(size_t)(c0 + c) * R + r0 + rq + i * 4] = o;
        }
    }
}

// ---------------- MFMA stage A: h = silu(x*Wg) * (x*Wu) ----------------
// 64x64 tile (g+u share A), BK=64, 4 waves 2x2, double-buffered prefetch.
__global__ __launch_bounds__(256) void moe_stage_a_mfma(
        const unsigned short* __restrict__ xb,    // [2048][2048]
        const unsigned short* __restrict__ wgt,   // [8][768][2048]
        const unsigned short* __restrict__ wut,   // [8][768][2048]
        const int* __restrict__ counts,
        const int* __restrict__ offsets,
        const int* __restrict__ row_token,
        unsigned short* __restrict__ h_buf) {     // [4224][768]
    int e = blockIdx.x, mt = blockIdx.y, nt = blockIdx.z;
    int count = counts[e];
    int m0 = mt * 64;
    if (m0 >= count) return;
    int off = offsets[e];
    int n0 = nt * 64;
    int mcnt = min(64, count - m0);
    int tid = threadIdx.x;

    __shared__ __align__(16) unsigned short As[2][64 * 64];
    __shared__ __align__(16) unsigned short Bg[2][64 * 64];
    __shared__ __align__(16) unsigned short Bu[2][64 * 64];
    __shared__ int toks[64];
    if (tid < 64) toks[tid] = row_token[off + m0 + min(tid, mcnt - 1)];
    __syncthreads();

    int w = tid >> 6, l = tid & 63;
    int wr = w >> 1, wc = w & 1;
    int lr = l & 15, lh = l >> 4;
    int rA = w * 8 + (l >> 3);    // staging row (0..31), +32 per issue
    int cA = l & 7;               // 16B chunk within 128B row

    const unsigned short* wgE = wgt + (size_t)e * FINT * HID + (size_t)n0 * HID;
    const unsigned short* wuE = wut + (size_t)e * FINT * HID + (size_t)n0 * HID;

    f32x4 gacc[2][2] = {};
    f32x4 uacc[2][2] = {};

    auto STAGE = [&](int buf, int k0) {
        #pragma unroll
        for (int i = 0; i < 2; ++i) {
            int row = 32 * i + rA;
            int sc = (cA ^ (row & 7)) << 3;      // pre-swizzled source offset
            size_t db = (size_t)(32 * i + w * 8) * 128;
            gl16(xb + (size_t)toks[row] * HID + k0 + sc, (char*)&As[buf][0] + db);
            gl16(wgE + (size_t)row * HID + k0 + sc,      (char*)&Bg[buf][0] + db);
            gl16(wuE + (size_t)row * HID + k0 + sc,      (char*)&Bu[buf][0] + db);
        }
    };

    auto COMPUTE = [&](int buf) {
        #pragma unroll
        for (int ks = 0; ks < 2; ++ks) {
            bf16x8 af[2], bg[2], bu[2];
            #pragma unroll
            for (int mi = 0; mi < 2; ++mi) {
                int row = wr * 32 + mi * 16 + lr;
                int byte = row * 128 + ((ks * 64 + lh * 16) ^ ((row & 7) << 4));
                af[mi] = *(const bf16x8*)((const char*)&As[buf][0] + byte);
            }
            #pragma unroll
            for (int ni = 0; ni < 2; ++ni) {
                int row = wc * 32 + ni * 16 + lr;
                int byte = row * 128 + ((ks * 64 + lh * 16) ^ ((row & 7) << 4));
                bg[ni] = *(const bf16x8*)((const char*)&Bg[buf][0] + byte);
                bu[ni] = *(const bf16x8*)((const char*)&Bu[buf][0] + byte);
            }
            #pragma unroll
            for (int mi = 0; mi < 2; ++mi)
                #pragma unroll
                for (int ni = 0; ni < 2; ++ni) {
                    gacc[mi][ni] = __builtin_amdgcn_mfma_f32_16x16x32_bf16(af[mi], bg[ni], gacc[mi][ni], 0, 0, 0);
                    uacc[mi][ni] = __builtin_amdgcn_mfma_f32_16x16x32_bf16(af[mi], bu[ni], uacc[mi][ni], 0, 0, 0);
                }
        }
    };

    STAGE(0, 0);
    __syncthreads();                   // drain buf0
    for (int t = 0; t < HID / 64; ++t) {
        int cur = t & 1;
        if (t + 1 < HID / 64) STAGE(cur ^ 1, (t + 1) * 64);  // prefetch next
        COMPUTE(cur);                  // overlap with in-flight loads
        __syncthreads();               // drain next-tile loads + guard reuse
    }

    #pragma unroll
    for (int mi = 0; mi < 2; ++mi)
        #pragma unroll
        for (int ni = 0; ni < 2; ++ni)
            #pragma unroll
            for (int j = 0; j < 4; ++j) {
                int row = wr * 32 + mi * 16 + lh * 4 + j;
                if (row < mcnt) {
                    int col = wc * 32 + ni * 16 + lr;
                    float g = gacc[mi][ni][j], u = uacc[mi][ni][j];
                    float hv = g / (1.f + expf(-g)) * u;
                    h_buf[(size_t)(off + m0 + row) * FINT + n0 + col] = f2bf(hv);
                }
            }
}

// ---------------- MFMA stage B: out[tok] += w * (h * Wd) ----------------
// m97 structure: 128x128 tile, BK=64, 4 waves 2x2, acc[4][4], double-buffered.
__global__ __launch_bounds__(256) void moe_stage_b_mfma(
        const unsigned short* __restrict__ h_buf, // [4224][768]
        const unsigned short* __restrict__ wdt,   // [8][2048][768]
        const int* __restrict__ counts,
        const int* __restrict__ offsets,
        const int* __restrict__ row_token,
        const float* __restrict__ row_w,
        float* __restrict__ out) {
    int e = blockIdx.x, mt = blockIdx.y, nt = blockIdx.z;
    int count = counts[e];
    int m0 = mt * 128;
    if (m0 >= count) return;
    int off = offsets[e];
    int n0 = nt * 128;
    int mcnt = min(128, count - m0);
    int tid = threadIdx.x;

    __shared__ __align__(16) unsigned short As[2][128 * 64];  // 32 KB
    __shared__ __align__(16) unsigned short Bs[2][128 * 64];  // 32 KB
    __shared__ int toks[128];
    __shared__ float rws[128];
    if (tid < 128) {
        int mm = min(tid, mcnt - 1);
        toks[tid] = row_token[off + m0 + mm];
        rws[tid] = row_w[off + m0 + mm];
    }
    __syncthreads();

    int w = tid >> 6, l = tid & 63;
    int wr = w >> 1, wc = w & 1;
    int lr = l & 15, lh = l >> 4;
    int wbase = (tid & 192) * 16;   // wave-uniform byte base within 4KB slab

    const unsigned short* hb = h_buf + (size_t)(off + m0) * FINT;
    const unsigned short* wdE = wdt + (size_t)e * HID * FINT + (size_t)n0 * FINT;

    f32x4 acc[4][4] = {};

    auto STAGE = [&](int buf, int k0) {
        #pragma unroll
        for (int i = 0; i < 4; ++i) {
            int s = i * 256 + tid;
            int row = s >> 3, c = s & 7;
            int sc = (c ^ (row & 7)) << 3;
            gl16(hb + (size_t)row * FINT + k0 + sc,  (char*)&As[buf][0] + i * 4096 + wbase);
            gl16(wdE + (size_t)row * FINT + k0 + sc, (char*)&Bs[buf][0] + i * 4096 + wbase);
        }
    };

    auto COMPUTE = [&](int buf) {
        #pragma unroll
        for (int ks = 0; ks < 2; ++ks) {
            bf16x8 af[4], bf[4];
            #pragma unroll
            for (int mi = 0; mi < 4; ++mi) {
                int row = wr * 64 + mi * 16 + lr;
                int byte = row * 128 + ((ks * 64 + lh * 16) ^ ((row & 7) << 4));
                af[mi] = *(const bf16x8*)((const char*)&As[buf][0] + byte);
            }
            #pragma unroll
            for (int ni = 0; ni < 4; ++ni) {
                int row = wc * 64 + ni * 16 + lr;
                int byte = row * 128 + ((ks * 64 + lh * 16) ^ ((row & 7) << 4));
                bf[ni] = *(const bf16x8*)((const char*)&Bs[buf][0] + byte);
            }
            #pragma unroll
            for (int mi = 0; mi < 4; ++mi)
                #pragma unroll
                for (int ni = 0; ni < 4; ++ni)
                    acc[mi][ni] = __builtin_amdgcn_mfma_f32_16x16x32_bf16(af[mi], bf[ni], acc[mi][ni], 0, 0, 0);
        }
    };

    STAGE(0, 0);
    __syncthreads();
    for (int t = 0; t < FINT / 64; ++t) {
        int cur = t & 1;
        if (t + 1 < FINT / 64) STAGE(cur ^ 1, (t + 1) * 64);
        COMPUTE(cur);
        __syncthreads();
    }

    #pragma unroll
    for (int mi = 0; mi < 4; ++mi)
        #pragma unroll
        for (int ni = 0; ni < 4; ++ni)
            #pragma unroll
            for (int j = 0; j < 4; ++j) {
                int row = wr * 64 + mi * 16 + lh * 4 + j;
                if (row < mcnt) {
                    int col = n0 + wc * 64 + ni * 16 + lr;
                    atomicAdd(&out[(size_t)toks[row] * HID + col],
                              rws[row] * acc[mi][ni][j]);
                }
            }
}

extern "C" void kernel_launch(void* const* d_in, const int* in_sizes, int n_in,
                              void* d_out, int out_size, void* d_ws, size_t ws_size,
                              hipStream_t stream) {
    const float* x       = (const float*)d_in[0];  // [2,1024,2048]
    const float* gate_w  = (const float*)d_in[1];  // [8,2048]
    const float* w_gate  = (const float*)d_in[2];  // [8,2048,768]
    const float* w_up    = (const float*)d_in[3];  // [8,2048,768]
    const float* w_down  = (const float*)d_in[4];  // [8,768,2048]
    float* out = (float*)d_out;                    // 2048*2048 out + 2048*8 logits

    char* ws = (char*)d_ws;
    int*   topk_idx  = (int*)  (ws + 0);
    float* topk_w    = (float*)(ws + 16384);
    int*   counts    = (int*)  (ws + 32768);
    int*   offsets   = (int*)  (ws + 32800);
    int*   row_token = (int*)  (ws + 33024);
    float* row_w     = (float*)(ws + 49408);
    int*   elist_t   = (int*)  (ws + 65792);
    float* elist_w   = (float*)(ws + 131328);

    unsigned short* xb   = (unsigned short*)(ws + 196864);
    unsigned short* wg_t = (unsigned short*)(ws + 8585472);
    unsigned short* wu_t = (unsigned short*)(ws + 33751296);
    unsigned short* wd_t = (unsigned short*)(ws + 58917120);
    unsigned short* hb   = (unsigned short*)(ws + 84082944);

    float* logits_out = out + (size_t)NTOK * HID;

    hipMemsetAsync(out, 0, (size_t)NTOK * HID * sizeof(float), stream);

    moe_router_cvt<<<NTOK / 4, 256, 0, stream>>>(x, gate_w, logits_out,
                                                 topk_idx, topk_w, xb);
    moe_build_kernel<<<1, 1024, 0, stream>>>(topk_idx, topk_w, counts, offsets,
                                             elist_t, elist_w, row_token, row_w);
    dim3 gT(1152, NEXP);
    transpose_cvt_all<<<gT, 256, 0, stream>>>(w_gate, w_up, w_down,
                                              wg_t, wu_t, wd_t);

    dim3 gridA(NEXP, NTOK / 64, FINT / 64);
    moe_stage_a_mfma<<<gridA, 256, 0, stream>>>(xb, wg_t, wu_t, counts, offsets,
                                                row_token, hb);
    dim3 gridB(NEXP, NTOK / 128, HID / 128);
    moe_stage_b_mfma<<<gridB, 256, 0, stream>>>(hb, wd_t, counts, offsets,
                                                row_token, row_w, out);
}